// Round 11
// baseline (440.528 us; speedup 1.0000x reference)
//
#include <hip/hip_runtime.h>
#include <hip/hip_bf16.h>

typedef __bf16 bf16x8 __attribute__((ext_vector_type(8)));
typedef float f32x4 __attribute__((ext_vector_type(4)));

constexpr int NE   = 16;
constexpr int NB   = 4096;
constexpr int INF  = 1024;
constexpr int OUTF = 1024;
constexpr int BM = 64, BN = 128, BK = 64;
constexpr int NSTEP  = INF / BK;    // 16 steps per K-half (split-K=2)
constexpr int ABYTES = BM * BK * 2; //  8 KiB A bf16 tile buffer
constexpr int BBYTES = BN * BK * 2; // 16 KiB B bf16 tile buffer
constexpr int MAXMT  = NB / BM;     // 64 worst-case M-tiles per expert

// f32x4 -> packed bf16x4 via scalar casts (RTNE); compiler fuses into
// v_cvt_pk_bf16_f32 pairs (m240: scalar-cast form beats hand-rolled asm).
__device__ __forceinline__ uint2 cvt4(const float4 v) {
  union { __bf16 h[4]; uint2 u; } r;
  r.h[0] = (__bf16)v.x; r.h[1] = (__bf16)v.y;
  r.h[2] = (__bf16)v.z; r.h[3] = (__bf16)v.w;
  return r.u;
}

__global__ void route_init_kernel(int* counts) {
  if (threadIdx.x < NE) counts[threadIdx.x] = 0;
}

__global__ void route_kernel(const int* __restrict__ eidx, int* counts, int* rows) {
  int i = blockIdx.x * blockDim.x + threadIdx.x;
  if (i < NB) {
    int e = eidx[i];
    int slot = atomicAdd(&counts[e], 1);
    rows[e * NB + slot] = i;
  }
}

// grid: (OUTF/BN, MAXMT, NE*2).  z = expert*2 + khalf.
// khalf=0: logits·W0 (+bias b0+b1), khalf=1: prior·W1. Exactly two
// commutative f32 atomicAdds per output element on a zeroed base.
__global__ __launch_bounds__(256, 3) void ens_gemm_kernel(
    const float* __restrict__ X0,    // logits     [NB, INF]
    const float* __restrict__ X1,    // prior      [NB, INF]
    const float* __restrict__ W0,    // [NE, OUTF, INF]
    const float* __restrict__ B0,    // [NE, OUTF]
    const float* __restrict__ W1,
    const float* __restrict__ B1,
    const int* __restrict__ counts,
    const int* __restrict__ rows,
    float* __restrict__ out)         // [NB, OUTF] (pre-zeroed)
{
  const int e  = blockIdx.z >> 1;
  const int kh = blockIdx.z & 1;
  const int mt = blockIdx.y;
  const int n0 = blockIdx.x * BN;
  const int me = counts[e];
  const int m0 = mt * BM;
  if (m0 >= me) return;              // dead tile — cheap early exit

  __shared__ __align__(16) char smem[2 * (ABYTES + BBYTES)]; // dbuf A+B (48 KiB)
  __shared__ int rid[BM];

  const int t = threadIdx.x;
  if (t < BM) {
    int slot = m0 + t;
    rid[t] = (slot < me) ? rows[e * NB + slot] : -1;
  }
  __syncthreads();

  const int tr = t >> 4;            // staging row-in-group 0..15
  const int tc = t & 15;            // staging float4 col   0..15
  const int w  = t >> 6;
  const int l  = t & 63;
  const int wm = (w >> 1) * 32;     // wave M origin in tile (2 waves in M)
  const int wn = (w & 1) * 64;      // wave N origin in tile (2 waves in N)
  const int lr = l & 15;
  const int lk = l >> 4;

  const float* xs = kh ? X1 : X0;
  const float* ws = (kh ? W1 : W0) + (size_t)e * OUTF * INF;

  int rcache[4];
#pragma unroll
  for (int p = 0; p < 4; ++p) rcache[p] = rid[p * 16 + tr];

  f32x4 acc[2][4] = {};

  // two named prefetch register sets (compile-time indexed — no scratch)
  float4 ra0[4], rw0[8], ra1[4], rw1[8];

  auto gload = [&](int s, float4 (&ra)[4], float4 (&rw)[8]) {
    const int kc = s * BK + tc * 4;
#pragma unroll
    for (int p = 0; p < 4; ++p) {
      const int r = rcache[p];
      ra[p] = (r >= 0) ? *(const float4*)(xs + (size_t)r * INF + kc)
                       : make_float4(0.f, 0.f, 0.f, 0.f);
    }
#pragma unroll
    for (int p = 0; p < 8; ++p)
      rw[p] = *(const float4*)(ws + (size_t)(n0 + p * 16 + tr) * INF + kc);
  };

  auto swrite = [&](char* base, float4 (&ra)[4], float4 (&rw)[8]) {
    char* ab = base;
    char* bb = base + ABYTES;
    const int c0 = tc * 8;          // byte col within 128 B row
#pragma unroll
    for (int p = 0; p < 4; ++p) {
      const int row = p * 16 + tr;
      *(uint2*)(ab + row * (BK * 2) + (c0 ^ ((row & 7) << 4))) = cvt4(ra[p]);
    }
#pragma unroll
    for (int p = 0; p < 8; ++p) {
      const int row = p * 16 + tr;
      *(uint2*)(bb + row * (BK * 2) + (c0 ^ ((row & 7) << 4))) = cvt4(rw[p]);
    }
  };

  auto compute = [&](const char* base) {
    const char* ab = base;
    const char* bb = base + ABYTES;
#pragma unroll
    for (int kk = 0; kk < 2; ++kk) {
      const int kb = kk * 64 + lk * 16;   // byte col of this lane's 8 bf16
      bf16x8 af[2], bv[4];
#pragma unroll
      for (int f = 0; f < 2; ++f) {
        const int arow = wm + f * 16 + lr;
        af[f] = *(const bf16x8*)(ab + arow * (BK * 2) + (kb ^ ((arow & 7) << 4)));
      }
#pragma unroll
      for (int f = 0; f < 4; ++f) {
        const int brow = wn + f * 16 + lr;
        bv[f] = *(const bf16x8*)(bb + brow * (BK * 2) + (kb ^ ((brow & 7) << 4)));
      }
#pragma unroll
      for (int fm = 0; fm < 2; ++fm)
#pragma unroll
        for (int fn = 0; fn < 4; ++fn)
          acc[fm][fn] = __builtin_amdgcn_mfma_f32_16x16x32_bf16(
              af[fm], bv[fn], acc[fm][fn], 0, 0, 0);
    }
  };

  char* buf0 = smem;
  char* buf1 = smem + (ABYTES + BBYTES);

  // prologue: fill buf0 (step 0), leave step-1 loads in flight
  gload(0, ra0, rw0);
  swrite(buf0, ra0, rw0);
  gload(1, ra1, rw1);
  __syncthreads();

  // steady state, manually unrolled x2. Set consumed by swrite(s+1) was
  // issued a full step earlier -> compiler waits with high vmcnt, newer
  // loads stay in flight across the barrier.
  for (int s = 0; s < NSTEP; s += 2) {
    if (s + 2 < NSTEP) gload(s + 2, ra0, rw0);
    compute(buf0);                       // step s
    swrite(buf1, ra1, rw1);              // stage step s+1
    __syncthreads();
    if (s + 3 < NSTEP) gload(s + 3, ra1, rw1);
    compute(buf1);                       // step s+1
    if (s + 2 < NSTEP) swrite(buf0, ra0, rw0);
    __syncthreads();
  }

  // epilogue: atomic accumulate (exactly 2 adds per element, commutative).
  const float* Bb0 = B0 + e * OUTF;
  const float* Bb1 = B1 + e * OUTF;
#pragma unroll
  for (int fn = 0; fn < 4; ++fn) {
    const int gcol = n0 + wn + fn * 16 + lr;
    const float bias = (kh == 0) ? (Bb0[gcol] + Bb1[gcol]) : 0.f;
#pragma unroll
    for (int fm = 0; fm < 2; ++fm) {
#pragma unroll
      for (int j = 0; j < 4; ++j) {
        const int sl = wm + fm * 16 + lk * 4 + j;   // slot in tile
        const int r = rid[sl];
        if (r >= 0) atomicAdd(&out[(size_t)r * OUTF + gcol], acc[fm][fn][j] + bias);
      }
    }
  }
}

extern "C" void kernel_launch(void* const* d_in, const int* in_sizes, int n_in,
                              void* d_out, int out_size, void* d_ws, size_t ws_size,
                              hipStream_t stream) {
  const float* logits = (const float*)d_in[0];
  const float* prior  = (const float*)d_in[1];
  const float* W      = (const float*)d_in[2];
  const float* b      = (const float*)d_in[3];
  const float* Wp     = (const float*)d_in[4];
  const float* bp     = (const float*)d_in[5];
  const int*   eidx   = (const int*)d_in[6];
  float* out = (float*)d_out;

  int* counts = (int*)d_ws;
  int* rows   = counts + 32;   // 128 B pad; rows needs NE*NB*4 = 256 KiB

  // split-K accumulates via atomics — output must start at exactly 0.f
  (void)hipMemsetAsync(d_out, 0, (size_t)out_size * sizeof(float), stream);

  hipLaunchKernelGGL(route_init_kernel, dim3(1), dim3(64), 0, stream, counts);
  hipLaunchKernelGGL(route_kernel, dim3(NB / 256), dim3(256), 0, stream,
                     eidx, counts, rows);

  dim3 grid(OUTF / BN, MAXMT, NE * 2);
  hipLaunchKernelGGL(ens_gemm_kernel, grid, dim3(256), 0, stream,
                     logits, prior, W, b, Wp, bp, counts, rows, out);
}

// Round 12
// 128.852 us; speedup vs baseline: 3.4189x; 3.4189x over previous
//
#include <hip/hip_runtime.h>
#include <hip/hip_bf16.h>

typedef __bf16 bf16x8 __attribute__((ext_vector_type(8)));
typedef float f32x4 __attribute__((ext_vector_type(4)));

constexpr int NE   = 16;
constexpr int NB   = 4096;
constexpr int INF  = 1024;
constexpr int OUTF = 1024;
constexpr int BM = 64, BN = 128, BK = 64;
constexpr int NSTEP  = INF / BK;    // 16 steps per K-half (split-K=2)
constexpr int ABYTES = BM * BK * 2; //  8 KiB A bf16 tile buffer
constexpr int BBYTES = BN * BK * 2; // 16 KiB B bf16 tile buffer
constexpr int MAXT   = NB / BM + NE - 1;  // 79: max live M-tiles across experts

// f32x4 -> packed bf16x4 via scalar casts (RTNE); compiler fuses into
// v_cvt_pk_bf16_f32 pairs (m240: scalar-cast form beats hand-rolled asm).
__device__ __forceinline__ uint2 cvt4(const float4 v) {
  union { __bf16 h[4]; uint2 u; } r;
  r.h[0] = (__bf16)v.x; r.h[1] = (__bf16)v.y;
  r.h[2] = (__bf16)v.z; r.h[3] = (__bf16)v.w;
  return r.u;
}

// ws layout: [0..15] counts, [16] ntiles, [32..32+MAXT) tile descriptors,
// [128..) rows (NE*NB ints)
__global__ void route_init_kernel(int* ws) {
  if (threadIdx.x < 32) ws[threadIdx.x] = 0;
}

__global__ void route_kernel(const int* __restrict__ eidx, int* counts, int* rows) {
  int i = blockIdx.x * blockDim.x + threadIdx.x;
  if (i < NB) {
    int e = eidx[i];
    int slot = atomicAdd(&counts[e], 1);
    rows[e * NB + slot] = i;
  }
}

// Build compact live-tile list: tiles[ti] = (e<<16) | mt. One wave.
__global__ void tile_kernel(int* ws) {
  int lane = threadIdx.x;              // 0..63
  int nt = 0;
  if (lane < NE) nt = (ws[lane] + BM - 1) / BM;   // tiles for expert `lane`
  // inclusive prefix over 16 lanes (wave-uniform shfl_up)
  int pre = nt;
  for (int d = 1; d < NE; d <<= 1) {
    int v = __shfl_up(pre, d);
    if (lane >= d && lane < NE) pre += v;
  }
  int total = __shfl(pre, NE - 1);
  if (lane == 0) ws[16] = total;
  if (lane < NE) {
    int base = pre - nt;
    for (int m = 0; m < nt; ++m) ws[32 + base + m] = (lane << 16) | m;
  }
}

// grid: (OUTF/BN, MAXT, 2).  z = khalf. blockIdx.y indexes the compact
// live-tile list (<=176 dead blocks vs ~15300 with the dense grid).
// khalf=0: logits·W0 (+bias b0+b1), khalf=1: prior·W1. Exactly two
// commutative f32 atomicAdds per output element on a zeroed base.
__global__ __launch_bounds__(256, 3) void ens_gemm_kernel(
    const float* __restrict__ X0,    // logits     [NB, INF]
    const float* __restrict__ X1,    // prior      [NB, INF]
    const float* __restrict__ W0,    // [NE, OUTF, INF]
    const float* __restrict__ B0,    // [NE, OUTF]
    const float* __restrict__ W1,
    const float* __restrict__ B1,
    const int* __restrict__ ws_i,    // counts/ntiles/tiles
    const int* __restrict__ rows,
    float* __restrict__ out)         // [NB, OUTF] (pre-zeroed)
{
  const int nt = ws_i[16];
  if (blockIdx.y >= nt) return;
  const int desc = ws_i[32 + blockIdx.y];
  const int e  = desc >> 16;
  const int m0 = (desc & 0xffff) * BM;
  const int kh = blockIdx.z;
  const int n0 = blockIdx.x * BN;
  const int me = ws_i[e];

  __shared__ __align__(16) char smem[2 * (ABYTES + BBYTES)]; // dbuf A+B (48 KiB)
  __shared__ int rid[BM];

  const int t = threadIdx.x;
  if (t < BM) {
    int slot = m0 + t;
    rid[t] = (slot < me) ? rows[e * NB + slot] : -1;
  }
  __syncthreads();

  const int tr = t >> 4;            // staging row-in-group 0..15
  const int tc = t & 15;            // staging float4 col   0..15
  const int w  = t >> 6;
  const int l  = t & 63;
  const int wm = (w >> 1) * 32;     // wave M origin in tile (2 waves in M)
  const int wn = (w & 1) * 64;      // wave N origin in tile (2 waves in N)
  const int lr = l & 15;
  const int lk = l >> 4;

  const float* xs = kh ? X1 : X0;
  const float* wsp = (kh ? W1 : W0) + (size_t)e * OUTF * INF;

  int rcache[4];
#pragma unroll
  for (int p = 0; p < 4; ++p) rcache[p] = rid[p * 16 + tr];

  f32x4 acc[2][4] = {};

  float4 ra[4], rw[8];              // single prefetch register set (no spill)

  auto gload = [&](int s) {
    const int kc = s * BK + tc * 4;
#pragma unroll
    for (int p = 0; p < 4; ++p) {
      const int r = rcache[p];
      ra[p] = (r >= 0) ? *(const float4*)(xs + (size_t)r * INF + kc)
                       : make_float4(0.f, 0.f, 0.f, 0.f);
    }
#pragma unroll
    for (int p = 0; p < 8; ++p)
      rw[p] = *(const float4*)(wsp + (size_t)(n0 + p * 16 + tr) * INF + kc);
  };

  auto swrite = [&](int buf) {
    char* ab = smem + buf * (ABYTES + BBYTES);
    char* bb = ab + ABYTES;
    const int c0 = tc * 8;          // byte col within 128 B row
#pragma unroll
    for (int p = 0; p < 4; ++p) {
      const int row = p * 16 + tr;
      *(uint2*)(ab + row * (BK * 2) + (c0 ^ ((row & 7) << 4))) = cvt4(ra[p]);
    }
#pragma unroll
    for (int p = 0; p < 8; ++p) {
      const int row = p * 16 + tr;
      *(uint2*)(bb + row * (BK * 2) + (c0 ^ ((row & 7) << 4))) = cvt4(rw[p]);
    }
  };

  auto compute = [&](int buf) {
    const char* ab = smem + buf * (ABYTES + BBYTES);
    const char* bb = ab + ABYTES;
#pragma unroll
    for (int kk = 0; kk < 2; ++kk) {
      const int kb = kk * 64 + lk * 16;   // byte col of this lane's 8 bf16
      bf16x8 af[2], bv[4];
#pragma unroll
      for (int f = 0; f < 2; ++f) {
        const int arow = wm + f * 16 + lr;
        af[f] = *(const bf16x8*)(ab + arow * (BK * 2) + (kb ^ ((arow & 7) << 4)));
      }
#pragma unroll
      for (int f = 0; f < 4; ++f) {
        const int brow = wn + f * 16 + lr;
        bv[f] = *(const bf16x8*)(bb + brow * (BK * 2) + (kb ^ ((brow & 7) << 4)));
      }
#pragma unroll
      for (int fm = 0; fm < 2; ++fm)
#pragma unroll
        for (int fn = 0; fn < 4; ++fn)
          acc[fm][fn] = __builtin_amdgcn_mfma_f32_16x16x32_bf16(
              af[fm], bv[fn], acc[fm][fn], 0, 0, 0);
    }
  };

  // prologue
  gload(0);
  swrite(0);
  __syncthreads();

  int cur = 0;
  for (int s = 0; s < NSTEP; ++s) {
    if (s + 1 < NSTEP) gload(s + 1);   // issue next-tile global loads early
    compute(cur);                      // ds_read + MFMA on current buffer
    if (s + 1 < NSTEP) swrite(cur ^ 1);// convert + ds_write into other buffer
    __syncthreads();
    cur ^= 1;
  }

  // epilogue: atomic accumulate (exactly 2 adds per element, commutative).
  const float* Bb0 = B0 + e * OUTF;
  const float* Bb1 = B1 + e * OUTF;
#pragma unroll
  for (int fn = 0; fn < 4; ++fn) {
    const int gcol = n0 + wn + fn * 16 + lr;
    const float bias = (kh == 0) ? (Bb0[gcol] + Bb1[gcol]) : 0.f;
#pragma unroll
    for (int fm = 0; fm < 2; ++fm) {
#pragma unroll
      for (int j = 0; j < 4; ++j) {
        const int sl = wm + fm * 16 + lk * 4 + j;   // slot in tile
        const int r = rid[sl];
        if (r >= 0) atomicAdd(&out[(size_t)r * OUTF + gcol], acc[fm][fn][j] + bias);
      }
    }
  }
}

extern "C" void kernel_launch(void* const* d_in, const int* in_sizes, int n_in,
                              void* d_out, int out_size, void* d_ws, size_t ws_size,
                              hipStream_t stream) {
  const float* logits = (const float*)d_in[0];
  const float* prior  = (const float*)d_in[1];
  const float* W      = (const float*)d_in[2];
  const float* b      = (const float*)d_in[3];
  const float* Wp     = (const float*)d_in[4];
  const float* bp     = (const float*)d_in[5];
  const int*   eidx   = (const int*)d_in[6];
  float* out = (float*)d_out;

  int* wsi  = (int*)d_ws;          // [0..15] counts, [16] ntiles, [32..] tiles
  int* rows = wsi + 128;           // NE*NB ints

  // split-K accumulates via atomics — output must start at exactly 0.f
  (void)hipMemsetAsync(d_out, 0, (size_t)out_size * sizeof(float), stream);

  hipLaunchKernelGGL(route_init_kernel, dim3(1), dim3(64), 0, stream, wsi);
  hipLaunchKernelGGL(route_kernel, dim3(NB / 256), dim3(256), 0, stream,
                     eidx, wsi, rows);
  hipLaunchKernelGGL(tile_kernel, dim3(1), dim3(64), 0, stream, wsi);

  dim3 grid(OUTF / BN, MAXT, 2);
  hipLaunchKernelGGL(ens_gemm_kernel, grid, dim3(256), 0, stream,
                     logits, prior, W, b, Wp, bp, wsi, rows, out);
}

// Round 13
// 108.441 us; speedup vs baseline: 4.0624x; 1.1882x over previous
//
#include <hip/hip_runtime.h>
#include <hip/hip_bf16.h>

typedef __bf16 bf16x8 __attribute__((ext_vector_type(8)));
typedef float f32x4 __attribute__((ext_vector_type(4)));

constexpr int NE   = 16;
constexpr int NB   = 4096;
constexpr int INF  = 1024;
constexpr int OUTF = 1024;
constexpr int BM = 64, BN = 128, BK = 32;
constexpr int NSTEP  = INF / BK;    // 32 steps per K-half (split-K=2)
constexpr int ABYTES = BM * BK * 4; //  8 KiB A f32 tile
constexpr int BBYTES = BN * BK * 4; // 16 KiB B f32 tile
constexpr int MAXMT  = NB / BM;     // 64 worst-case M-tiles per expert

// f32x4 pair -> bf16x8 (RTNE scalar casts; compiler fuses to v_cvt_pk_bf16_f32)
__device__ __forceinline__ bf16x8 cvt8(const f32x4 lo, const f32x4 hi) {
  bf16x8 r;
  r[0] = (__bf16)lo[0]; r[1] = (__bf16)lo[1];
  r[2] = (__bf16)lo[2]; r[3] = (__bf16)lo[3];
  r[4] = (__bf16)hi[0]; r[5] = (__bf16)hi[1];
  r[6] = (__bf16)hi[2]; r[7] = (__bf16)hi[3];
  return r;
}

// async global->LDS DMA, 16 B per lane. Dest is wave-uniform base; HW writes
// lane i at base + i*16. Source is per-lane (gather + pre-swizzle legal).
__device__ __forceinline__ void glds16(const float* g, char* l) {
  __builtin_amdgcn_global_load_lds(
      (const __attribute__((address_space(1))) void*)g,
      (__attribute__((address_space(3))) void*)l, 16, 0, 0);
}

__global__ void route_init_kernel(int* counts) {
  if (threadIdx.x < NE) counts[threadIdx.x] = 0;
}

__global__ void route_kernel(const int* __restrict__ eidx, int* counts, int* rows) {
  int i = blockIdx.x * blockDim.x + threadIdx.x;
  if (i < NB) {
    int e = eidx[i];
    int slot = atomicAdd(&counts[e], 1);
    rows[e * NB + slot] = i;
  }
}

// grid: (OUTF/BN, MAXMT, NE*2), z = expert*2 + khalf (dense R8 grid — the
// compact worklist of R12 hurt L2 locality). khalf=0: logits·W0 (+bias),
// khalf=1: prior·W1. Exactly two commutative f32 atomicAdds per output
// element on a zeroed base => deterministic.
__global__ __launch_bounds__(256, 3) void ens_gemm_kernel(
    const float* __restrict__ X0,    // logits     [NB, INF]
    const float* __restrict__ X1,    // prior      [NB, INF]
    const float* __restrict__ W0,    // [NE, OUTF, INF]
    const float* __restrict__ B0,    // [NE, OUTF]
    const float* __restrict__ W1,
    const float* __restrict__ B1,
    const int* __restrict__ counts,
    const int* __restrict__ rows,
    const float* __restrict__ zrow,  // 4 KiB of zeros (dead-row source)
    float* __restrict__ out)         // [NB, OUTF] (pre-zeroed)
{
  const int e  = blockIdx.z >> 1;
  const int kh = blockIdx.z & 1;
  const int mt = blockIdx.y;
  const int n0 = blockIdx.x * BN;
  const int me = counts[e];
  const int m0 = mt * BM;
  if (m0 >= me) return;              // dead tile — cheap early exit

  __shared__ __align__(16) char smem[2 * (ABYTES + BBYTES)]; // dbuf A+B (48 KiB)
  __shared__ int rid[BM];

  const int t = threadIdx.x;
  if (t < BM) rid[t] = (m0 + t < me) ? rows[e * NB + m0 + t] : -1;
  __syncthreads();

  const int w  = t >> 6;
  const int l  = t & 63;
  const int lr = l & 15;
  const int lk = l >> 4;
  const int wm = (w >> 1) * 32;     // wave M origin (2 waves in M)
  const int wn = (w & 1) * 64;      // wave N origin (2 waves in N)

  const float* xs  = kh ? X1 : X0;
  const float* wsp = (kh ? W1 : W0) + (size_t)e * OUTF * INF;

  // Staging: each 1 KiB LDS chunk = 8 rows x 128 B (one K=32 f32 slice).
  // Lane l covers row (l>>3) of its chunk at swizzled 16B-slot (l&7):
  // content for swizzled col c' comes from real col c' ^ (row&7)<<4, i.e.
  // float offset 4*((l&7) ^ ((l>>3)&7)).  (linear dest + inv-swz source)
  const int sub = l >> 3;
  const int swz = 4 * ((l & 7) ^ (sub & 7));

  const int ar0 = (2 * w) * 8 + sub;       // A rows this wave stages
  const int ar1 = (2 * w + 1) * 8 + sub;
  const int r0 = rid[ar0], r1 = rid[ar1];
  const float* pa0 = ((r0 >= 0) ? xs + (size_t)r0 * INF : zrow) + swz;
  const float* pa1 = ((r1 >= 0) ? xs + (size_t)r1 * INF : zrow) + swz;
  const float* pb0 = wsp + (size_t)(n0 + (4 * w)     * 8 + sub) * INF + swz;
  const float* pb1 = wsp + (size_t)(n0 + (4 * w + 1) * 8 + sub) * INF + swz;
  const float* pb2 = wsp + (size_t)(n0 + (4 * w + 2) * 8 + sub) * INF + swz;
  const float* pb3 = wsp + (size_t)(n0 + (4 * w + 3) * 8 + sub) * INF + swz;

  f32x4 acc[2][4] = {};

  auto stage = [&](char* base, int s) {
    char* ab = base;
    char* bb = base + ABYTES;
    const int o = s * BK;            // float offset of this K-slice
    glds16(pa0 + o, ab + (2 * w) * 1024);
    glds16(pa1 + o, ab + (2 * w + 1) * 1024);
    glds16(pb0 + o, bb + (4 * w) * 1024);
    glds16(pb1 + o, bb + (4 * w + 1) * 1024);
    glds16(pb2 + o, bb + (4 * w + 2) * 1024);
    glds16(pb3 + o, bb + (4 * w + 3) * 1024);
  };

  auto compute = [&](const char* base) {
    const char* ab = base;
    const char* bb = base + ABYTES;
    bf16x8 af[2], bv[4];
#pragma unroll
    for (int f = 0; f < 2; ++f) {
      const int row = wm + f * 16 + lr;
      const int c0 = (lk * 32) ^ ((row & 7) << 4);   // swizzled byte col
      f32x4 lo = *(const f32x4*)(ab + row * 128 + c0);
      f32x4 hi = *(const f32x4*)(ab + row * 128 + (c0 ^ 16));
      af[f] = cvt8(lo, hi);
    }
#pragma unroll
    for (int f = 0; f < 4; ++f) {
      const int row = wn + f * 16 + lr;
      const int c0 = (lk * 32) ^ ((row & 7) << 4);
      f32x4 lo = *(const f32x4*)(bb + row * 128 + c0);
      f32x4 hi = *(const f32x4*)(bb + row * 128 + (c0 ^ 16));
      bv[f] = cvt8(lo, hi);
    }
#pragma unroll
    for (int fm = 0; fm < 2; ++fm)
#pragma unroll
      for (int fn = 0; fn < 4; ++fn)
        acc[fm][fn] = __builtin_amdgcn_mfma_f32_16x16x32_bf16(
            af[fm], bv[fn], acc[fm][fn], 0, 0, 0);
  };

  char* b0 = smem;
  char* b1 = smem + (ABYTES + BBYTES);

  stage(b0, 0);
  __syncthreads();                   // compiler drains vmcnt before barrier

  for (int s = 0; s < NSTEP; ++s) {
    char* cur = (s & 1) ? b1 : b0;
    char* nxt = (s & 1) ? b0 : b1;
    if (s + 1 < NSTEP) stage(nxt, s + 1);  // fire-and-forget DMA
    compute(cur);                           // ds_read + cvt + MFMA
    __syncthreads();
  }

  // epilogue: atomic accumulate (exactly 2 adds per element, commutative)
  const float* Bb0 = B0 + e * OUTF;
  const float* Bb1 = B1 + e * OUTF;
#pragma unroll
  for (int fn = 0; fn < 4; ++fn) {
    const int gcol = n0 + wn + fn * 16 + lr;
    const float bias = (kh == 0) ? (Bb0[gcol] + Bb1[gcol]) : 0.f;
#pragma unroll
    for (int fm = 0; fm < 2; ++fm) {
#pragma unroll
      for (int j = 0; j < 4; ++j) {
        const int sl = wm + fm * 16 + lk * 4 + j;   // slot in tile
        const int r = rid[sl];
        if (r >= 0) atomicAdd(&out[(size_t)r * OUTF + gcol], acc[fm][fn][j] + bias);
      }
    }
  }
}

extern "C" void kernel_launch(void* const* d_in, const int* in_sizes, int n_in,
                              void* d_out, int out_size, void* d_ws, size_t ws_size,
                              hipStream_t stream) {
  const float* logits = (const float*)d_in[0];
  const float* prior  = (const float*)d_in[1];
  const float* W      = (const float*)d_in[2];
  const float* b      = (const float*)d_in[3];
  const float* Wp     = (const float*)d_in[4];
  const float* bp     = (const float*)d_in[5];
  const int*   eidx   = (const int*)d_in[6];
  float* out = (float*)d_out;

  int* counts = (int*)d_ws;
  int* rows   = counts + 32;                 // NE*NB ints
  float* zrow = (float*)(rows + NE * NB);    // 4 KiB zero page

  // split-K accumulates via atomics — output must start at exactly 0.f
  (void)hipMemsetAsync(d_out, 0, (size_t)out_size * sizeof(float), stream);
  (void)hipMemsetAsync(zrow, 0, 4096, stream);

  hipLaunchKernelGGL(route_init_kernel, dim3(1), dim3(64), 0, stream, counts);
  hipLaunchKernelGGL(route_kernel, dim3(NB / 256), dim3(256), 0, stream,
                     eidx, counts, rows);

  dim3 grid(OUTF / BN, MAXMT, NE * 2);
  hipLaunchKernelGGL(ens_gemm_kernel, grid, dim3(256), 0, stream,
                     logits, prior, W, b, Wp, bp, counts, rows, zrow, out);
}